// Round 10
// baseline (293.464 us; speedup 1.0000x reference)
//
#include <hip/hip_runtime.h>
#include <hip/hip_bf16.h>

#define NB 16
#define CDIM 256
#define NHEADS 8
#define DH 32
#define NSP 4096
#define O3 768

typedef __bf16 bf16;
typedef bf16 bf16x4 __attribute__((ext_vector_type(4)));
typedef bf16 bf16x8 __attribute__((ext_vector_type(8)));
typedef float f32x4 __attribute__((ext_vector_type(4)));
typedef float f32x16 __attribute__((ext_vector_type(16)));

static __device__ __forceinline__ float bf2f(bf16 x){ return (float)x; }
static __device__ __forceinline__ bf16 f2bf(float x){ return (bf16)x; }

// async global->LDS, 16B per lane; lds dst wave-uniform base + lane*16
static __device__ __forceinline__ void gld16(const bf16* g, bf16* l){
    __builtin_amdgcn_global_load_lds((const __attribute__((address_space(1))) void*)g,
                                     (__attribute__((address_space(3))) void*)l, 16, 0, 0);
}

// ---------------- K0: transpose+convert x[b][c][n] (fp32) -> xT[b][n][c] (bf16) ----------------
__global__ void k_transpose(const float* __restrict__ x, bf16* __restrict__ xT){
    __shared__ bf16 tile[64][72];
    int b = blockIdx.z;
    int c0 = blockIdx.y * 64;
    int n0 = blockIdx.x * 64;
    int t = threadIdx.x;
    const float* xb = x + (size_t)b * CDIM * NSP;
    #pragma unroll
    for (int i = 0; i < 4; ++i){
        int lin = i*256 + t;
        int c = lin >> 4;
        int n4 = (lin & 15) * 4;
        f32x4 f = *(const f32x4*)(xb + (size_t)(c0 + c)*NSP + n0 + n4);
        bf16x4 v4;
        #pragma unroll
        for (int j = 0; j < 4; ++j) v4[j] = f2bf(f[j]);
        *(bf16x4*)&tile[c][n4] = v4;
    }
    __syncthreads();
    bf16* xTb = xT + (size_t)b * NSP * CDIM;
    #pragma unroll
    for (int i = 0; i < 2; ++i){
        int lin = i*256 + t;
        int n = lin >> 3;
        int c8 = (lin & 7) * 8;
        bf16x8 v;
        #pragma unroll
        for (int j = 0; j < 8; ++j) v[j] = tile[c8+j][n];
        *(bf16x8*)(xTb + (size_t)(n0+n)*CDIM + c0 + c8) = v;
    }
}

// ---------------- K0b: convert w_qkv fp32 -> bf16 ----------------
__global__ void k_wcvt(const float* __restrict__ w, bf16* __restrict__ w2){
    int idx = (blockIdx.x*256 + threadIdx.x) * 4;
    f32x4 f = *(const f32x4*)(w + idx);
    bf16x4 v;
    #pragma unroll
    for (int j=0;j<4;j++) v[j] = f2bf(f[j]);
    *(bf16x4*)(w2 + idx) = v;
}

// ---------------- K2: fused k/v GEMM + k softmax + context partials, 128-n panels ----------------
// Block: one 128-n panel (64KB Bs) x all 512 k/v rows. 1024 thr = 16 waves;
// wave = 32 o x 128 n, acc[2][8], 128 MFMA. Waves 0-7: k (rows 256..511), 8-15: v (512..767).
// k softmax per 64-wide y-line (two lines per panel, R1 grp pattern).
// 2 phases x 4 heads: dump k_sm/v to cb[128][128] each (XOR-swz, 64KB), ctx via mfma 32x32x16
// (8 MFMA per head over n=128), write fp32 partials ctx_p[b][h][ntile][32][32]. kv never in HBM.
__global__ __launch_bounds__(1024,4) void k_kvctx(const bf16* __restrict__ w2,
                                                  const bf16* __restrict__ xT,
                                                  float* __restrict__ ctx_p){
    __shared__ union {
        bf16 Bs[32768];      // 128 rows * 32 slots * 8 el = 64 KB
        bf16 cb[32768];      // k_sm[128][128] @ el 0, v[128][128] @ el 16384
    } sm;
    int bid = blockIdx.x;
    int xcd = bid & 7, slot = bid >> 3;      // 64 slots per XCD
    int g = xcd*64 + slot;                   // 0..511
    int b = g >> 5;
    int ntile = g & 31;
    int n0 = ntile * 128;
    int t = threadIdx.x;
    int wv = t >> 6, lane = t & 63;

    // ---- stage panel [128 n][256 c]: per wave 4 gld16 (rows wv*8 .. wv*8+7) ----
    #pragma unroll
    for (int j=0;j<4;j++){
        int base_r = wv*8 + j*2;
        int r = base_r + (lane>>5);
        int c = (lane & 31) ^ (r & 7);
        gld16(xT + ((size_t)b*NSP + n0 + r)*CDIM + c*8, &sm.Bs[(size_t)base_r*256]);
    }
    __syncthreads();

    int brow[8], brx[8];
    #pragma unroll
    for (int ni=0;ni<8;ni++){
        int r = ni*16 + (lane&15);
        brow[ni] = r*32; brx[ni] = r & 7;
    }
    int arow = 256 + wv*32 + (lane&15);      // waves 0-7: k (256..511); 8-15: v (512..767)
    int acol = (lane>>4)*8;

    f32x4 acc[2][8];
    #pragma unroll
    for (int i=0;i<16;i++) ((f32x4*)acc)[i] = (f32x4){0.f,0.f,0.f,0.f};

    bf16x8 af0 = *(const bf16x8*)(w2 + (size_t)(arow     )*CDIM + acol);
    bf16x8 af1 = *(const bf16x8*)(w2 + (size_t)(arow + 16)*CDIM + acol);
    #pragma unroll
    for (int k0=0;k0<8;k0++){
        bf16x8 an0, an1;
        if (k0 < 7){
            an0 = *(const bf16x8*)(w2 + (size_t)(arow     )*CDIM + (k0+1)*32 + acol);
            an1 = *(const bf16x8*)(w2 + (size_t)(arow + 16)*CDIM + (k0+1)*32 + acol);
        }
        int cbase = (lane>>4) + k0*4;
        bf16x8 bfr[8];
        #pragma unroll
        for (int ni=0;ni<8;ni++)
            bfr[ni] = *(const bf16x8*)&sm.Bs[(size_t)(brow[ni] + (cbase ^ brx[ni]))*8];
        #pragma unroll
        for (int ni=0;ni<8;ni++)
            acc[0][ni] = __builtin_amdgcn_mfma_f32_16x16x32_bf16(af0, bfr[ni], acc[0][ni], 0, 0, 0);
        #pragma unroll
        for (int ni=0;ni<8;ni++)
            acc[1][ni] = __builtin_amdgcn_mfma_f32_16x16x32_bf16(af1, bfr[ni], acc[1][ni], 0, 0, 0);
        af0 = an0; af1 = an1;
    }

    // ---- k softmax over y-lines (waves 0-7): grp 0 = ni 0..3 (n 0..63), grp 1 = ni 4..7 ----
    if (wv < 8){
        #pragma unroll
        for (int mi=0;mi<2;mi++)
            #pragma unroll
            for (int r=0;r<4;r++)
                #pragma unroll
                for (int grp=0;grp<2;grp++){
                    float mx = -1e30f;
                    #pragma unroll
                    for (int q=0;q<4;q++) mx = fmaxf(mx, acc[mi][grp*4+q][r]);
                    #pragma unroll
                    for (int msk=1; msk<16; msk<<=1) mx = fmaxf(mx, __shfl_xor(mx, msk, 64));
                    float s = 0.f;
                    #pragma unroll
                    for (int q=0;q<4;q++){
                        float e = __expf(acc[mi][grp*4+q][r] - mx);
                        acc[mi][grp*4+q][r] = e; s += e;
                    }
                    #pragma unroll
                    for (int msk=1; msk<16; msk<<=1) s += __shfl_xor(s, msk, 64);
                    float inv = 1.f/s;
                    #pragma unroll
                    for (int q=0;q<4;q++) acc[mi][grp*4+q][r] *= inv;
                }
    }

    // ---- 2 phases x 4 heads: dump + ctx ----
    #pragma unroll
    for (int ph=0; ph<2; ++ph){
        __syncthreads();   // Bs dead (ph0) / prev-phase cb reads done (ph1)
        if (((wv>>2)&1) == ph){       // dumping waves this phase: k wv ph*4..+3, v wv 8+ph*4..+3
            int isv  = wv >> 3;
            int w03  = wv & 3;
            int base = isv * 16384;
            #pragma unroll
            for (int mi=0;mi<2;mi++)
                #pragma unroll
                for (int ni=0;ni<8;ni++)
                    #pragma unroll
                    for (int r=0;r<4;r++){
                        int row = w03*32 + mi*16 + (lane>>4)*4 + r;   // 0..127 in-phase
                        int n = ni*16 + (lane&15);
                        sm.cb[base + row*128 + (((n>>3) ^ (row&15))<<3) + (n&7)] = f2bf(acc[mi][ni][r]);
                    }
        }
        __syncthreads();
        if (wv < 4){
            // ctx for head h = ph*4 + wv: ctx[d][e] = sum_n k_sm[d][n] * v[e][n]
            f32x16 cacc;
            #pragma unroll
            for (int i=0;i<16;i++) cacc[i] = 0.f;
            int rr = wv*32 + (lane&31);
            #pragma unroll
            for (int s=0;s<8;s++){
                int nseg = s*2 + (lane>>5);
                int off = rr*128 + (((nseg ^ (rr&15))<<3));
                bf16x8 ka = *(const bf16x8*)&sm.cb[off];
                bf16x8 vb = *(const bf16x8*)&sm.cb[16384 + off];
                cacc = __builtin_amdgcn_mfma_f32_32x32x16_bf16(ka, vb, cacc, 0, 0, 0);
            }
            float* dst = ctx_p + ((size_t)(b*8 + ph*4 + wv)*32 + ntile)*1024;
            #pragma unroll
            for (int r=0;r<16;r++){
                int d = (r&3) + 8*(r>>2) + 4*(lane>>5);
                dst[d*32 + (lane&31)] = cacc[r];
            }
        }
    }
}

// ---------------- K5: reduce 32 partials + W2 = w_out x ctx (per b,h) ----------------
__global__ void k_merge(const float* __restrict__ w_out, const float* __restrict__ ctx_p,
                        bf16* __restrict__ W2){
    __shared__ float ctxs[32][32];
    int bh = blockIdx.x;
    int b = bh >> 3, h = bh & 7;
    int t = threadIdx.x;
    const float* base = ctx_p + (size_t)bh*32*1024;
    #pragma unroll
    for (int i=0;i<4;i++){
        int idx = i*256 + t;
        float s0 = 0.f, s1 = 0.f;
        #pragma unroll
        for (int p=0;p<16;p++){ s0 += base[(2*p)*1024 + idx]; s1 += base[(2*p+1)*1024 + idx]; }
        ((float*)ctxs)[idx] = s0 + s1;
    }
    __syncthreads();
    int o = t;
    const float* wrow = w_out + (size_t)o*CDIM + h*DH;
    float wv[32];
    #pragma unroll
    for (int d=0;d<32;d++) wv[d] = wrow[d];
    bf16* dst = W2 + ((size_t)b*CDIM + o)*CDIM + h*DH;
    #pragma unroll
    for (int g=0;g<4;g++){
        bf16x8 o8;
        #pragma unroll
        for (int jj=0;jj<8;jj++){
            int e = g*8 + jj;
            float s = 0.f;
            #pragma unroll
            for (int d=0;d<32;d++) s += wv[d]*ctxs[d][e];
            o8[jj] = f2bf(s);
        }
        *(bf16x8*)(dst + g*8) = o8;
    }
}

// ---------------- K6: fused q GEMM + q softmax + out GEMM + bias + register-LN ----------------
// Block: 32-n panel. Phase A: stage xT[n0..n0+32][0..256] (16KB); q-GEMM (acc[4][2]).
// q softmax per head (hp pattern). Phase B: dump q~ to swizzled slot format (16KB).
// Phase C: out-GEMM A=W2[b] global, B=q~ LDS, acc2[4][2].
// Phase D: LN stats in-register (shfl 16/32 + tiny red LDS), normalize in-register,
// then COALESCED writes via Yh[128][33] fp32 overlay in two o-phases (packed-row mapping
// o_act = (row>>5)*64 + p*32 + (row&31)): 32 threads emit full 128B lines per row.
// LDS union ~18KB -> 8 blocks/CU.
__global__ __launch_bounds__(256,8) void k_qout_ln(const bf16* __restrict__ w2,
                                                   const bf16* __restrict__ xT,
                                                   const bf16* __restrict__ W2,
                                                   const float* __restrict__ bout,
                                                   const float* __restrict__ gamma,
                                                   const float* __restrict__ beta,
                                                   float* __restrict__ out){
    __shared__ union {
        bf16 Bs[8192];        // 32 rows * 32 slots * 8 el = 16 KB (xT panel, then q~)
        float Yh[128*33];     // 16.9 KB half-Y epilogue buffer
    } sm;
    __shared__ float red[2][4][2][16];
    __shared__ float mu_s[32], rstd_s[32];
    int bid = blockIdx.x;
    int xcd = bid & 7, slot = bid >> 3;      // 256 slots per XCD
    int b  = slot >> 4;
    int n0 = (xcd*16 + (slot & 15)) * 32;
    int t = threadIdx.x, wv = t>>6, lane = t&63;

    // ---- stage xT panel [n0..n0+32][0..256]: per wave 4 gld16 (rows wv*8..wv*8+7) ----
    const bf16* xTb = xT + (size_t)b * NSP * CDIM;
    #pragma unroll
    for (int j=0;j<4;j++){
        int base_r = wv*8 + j*2;
        int r = base_r + (lane>>5);
        int c = (lane & 31) ^ (r & 7);
        gld16(xTb + (size_t)(n0 + r)*CDIM + c*8, &sm.Bs[(size_t)base_r*256]);
    }
    __syncthreads();

    int brow[2], brx[2];
    #pragma unroll
    for (int ni=0;ni<2;ni++){
        int r = ni*16 + (lane&15);
        brow[ni] = r*32; brx[ni] = r & 7;
    }
    int arow = wv*64 + (lane&15);
    int acol = (lane>>4)*8;

    // ---- Phase A: q-GEMM, A = w2 q-rows (0..255) ----
    f32x4 acc[4][2];
    #pragma unroll
    for (int i=0;i<8;i++) ((f32x4*)acc)[i] = (f32x4){0.f,0.f,0.f,0.f};
    {
        bf16x8 af[4], an[4];
        #pragma unroll
        for (int mi=0;mi<4;mi++)
            af[mi] = *(const bf16x8*)(w2 + (size_t)(arow + mi*16)*CDIM + acol);
        #pragma unroll
        for (int k0=0;k0<8;k0++){
            if (k0 < 7){
                #pragma unroll
                for (int mi=0;mi<4;mi++)
                    an[mi] = *(const bf16x8*)(w2 + (size_t)(arow + mi*16)*CDIM + (k0+1)*32 + acol);
            }
            int cbase = (lane>>4) + k0*4;
            bf16x8 bfr[2];
            #pragma unroll
            for (int ni=0;ni<2;ni++)
                bfr[ni] = *(const bf16x8*)&sm.Bs[(size_t)(brow[ni] + (cbase ^ brx[ni]))*8];
            #pragma unroll
            for (int mi=0;mi<4;mi++)
                #pragma unroll
                for (int ni=0;ni<2;ni++)
                    acc[mi][ni] = __builtin_amdgcn_mfma_f32_16x16x32_bf16(af[mi], bfr[ni], acc[mi][ni], 0, 0, 0);
            #pragma unroll
            for (int mi=0;mi<4;mi++) af[mi] = an[mi];
        }
    }

    // ---- q softmax over d; wave's 64 o-rows = heads 2wv (mi 0,1), 2wv+1 (mi 2,3) ----
    #pragma unroll
    for (int ni=0;ni<2;ni++)
        #pragma unroll
        for (int hp=0;hp<2;hp++){
            float mx = -1e30f;
            #pragma unroll
            for (int mi=2*hp; mi<2*hp+2; mi++)
                #pragma unroll
                for (int r=0;r<4;r++) mx = fmaxf(mx, acc[mi][ni][r]);
            mx = fmaxf(mx, __shfl_xor(mx, 16, 64));
            mx = fmaxf(mx, __shfl_xor(mx, 32, 64));
            float s = 0.f;
            #pragma unroll
            for (int mi=2*hp; mi<2*hp+2; mi++)
                #pragma unroll
                for (int r=0;r<4;r++){
                    float e = __expf(acc[mi][ni][r] - mx);
                    acc[mi][ni][r] = e; s += e;
                }
            s += __shfl_xor(s, 16, 64);
            s += __shfl_xor(s, 32, 64);
            float inv = 1.f/s;
            #pragma unroll
            for (int mi=2*hp; mi<2*hp+2; mi++)
                #pragma unroll
                for (int r=0;r<4;r++) acc[mi][ni][r] *= inv;
        }

    // ---- Phase B: dump q~ into swizzled slot format: slot(n,cseg)=n*32+(cseg^(n&7)) ----
    __syncthreads();   // Bs (xT panel) dead
    #pragma unroll
    for (int mi=0;mi<4;mi++)
        #pragma unroll
        for (int ni=0;ni<2;ni++){
            int n_loc = ni*16 + (lane&15);
            int cseg  = wv*8 + mi*2 + (lane>>5);          // (o>>3), o = wv*64+mi*16+(lane>>4)*4
            bf16x4 v4;
            #pragma unroll
            for (int r=0;r<4;r++) v4[r] = f2bf(acc[mi][ni][r]);
            *(bf16x4*)&sm.Bs[(size_t)(n_loc*32 + (cseg ^ (n_loc&7)))*8 + ((lane>>4)&1)*4] = v4;
        }
    __syncthreads();

    // ---- Phase C: out-GEMM, A = W2[b] (global, L2-hot), B = q~ (LDS) ----
    const bf16* Ab = W2 + (size_t)b*CDIM*CDIM;
    f32x4 acc2[4][2];
    #pragma unroll
    for (int i=0;i<8;i++) ((f32x4*)acc2)[i] = (f32x4){0.f,0.f,0.f,0.f};
    {
        bf16x8 af[4], an[4];
        #pragma unroll
        for (int mi=0;mi<4;mi++)
            af[mi] = *(const bf16x8*)(Ab + (size_t)(arow + mi*16)*CDIM + acol);
        #pragma unroll
        for (int k0=0;k0<8;k0++){
            if (k0 < 7){
                #pragma unroll
                for (int mi=0;mi<4;mi++)
                    an[mi] = *(const bf16x8*)(Ab + (size_t)(arow + mi*16)*CDIM + (k0+1)*32 + acol);
            }
            int cbase = (lane>>4) + k0*4;
            bf16x8 bfr[2];
            #pragma unroll
            for (int ni=0;ni<2;ni++)
                bfr[ni] = *(const bf16x8*)&sm.Bs[(size_t)(brow[ni] + (cbase ^ brx[ni]))*8];
            #pragma unroll
            for (int mi=0;mi<4;mi++)
                #pragma unroll
                for (int ni=0;ni<2;ni++)
                    acc2[mi][ni] = __builtin_amdgcn_mfma_f32_16x16x32_bf16(af[mi], bfr[ni], acc2[mi][ni], 0, 0, 0);
            #pragma unroll
            for (int mi=0;mi<4;mi++) af[mi] = an[mi];
        }
    }

    // ---- Phase D: LN stats + normalize in-register ----
    // lane's o-rows: o = wv*64 + mi*16 + (lane>>4)*4 + r; n = ni*16 + (lane&15).
    float sA[2] = {0.f, 0.f}, sB[2] = {0.f, 0.f};
    #pragma unroll
    for (int mi=0;mi<4;mi++){
        f32x4 b4 = *(const f32x4*)&bout[wv*64 + mi*16 + (lane>>4)*4];
        #pragma unroll
        for (int ni=0;ni<2;ni++)
            #pragma unroll
            for (int r=0;r<4;r++){
                float y = acc2[mi][ni][r] + b4[r];
                acc2[mi][ni][r] = y;
                sA[ni] += y; sB[ni] += y*y;
            }
    }
    #pragma unroll
    for (int ni=0;ni<2;ni++){
        sA[ni] += __shfl_xor(sA[ni], 16, 64); sA[ni] += __shfl_xor(sA[ni], 32, 64);
        sB[ni] += __shfl_xor(sB[ni], 16, 64); sB[ni] += __shfl_xor(sB[ni], 32, 64);
    }
    if (lane < 16){
        #pragma unroll
        for (int ni=0;ni<2;ni++){
            red[0][wv][ni][lane] = sA[ni];
            red[1][wv][ni][lane] = sB[ni];
        }
    }
    __syncthreads();
    if (t < 32){
        float S = 0.f, S2 = 0.f;
        #pragma unroll
        for (int w=0;w<4;w++){ S += red[0][w][t>>4][t&15]; S2 += red[1][w][t>>4][t&15]; }
        float mu = S * (1.f/256.f);
        float var = S2*(1.f/256.f) - mu*mu;
        mu_s[t] = mu; rstd_s[t] = rsqrtf(var + 1e-5f);
    }
    __syncthreads();
    float mu[2], rs[2];
    #pragma unroll
    for (int ni=0;ni<2;ni++){
        mu[ni] = mu_s[ni*16 + (lane&15)];
        rs[ni] = rstd_s[ni*16 + (lane&15)];
    }
    #pragma unroll
    for (int mi=0;mi<4;mi++){
        int o0 = wv*64 + mi*16 + (lane>>4)*4;
        f32x4 g4  = *(const f32x4*)&gamma[o0];
        f32x4 be4 = *(const f32x4*)&beta[o0];
        #pragma unroll
        for (int ni=0;ni<2;ni++)
            #pragma unroll
            for (int r=0;r<4;r++)
                acc2[mi][ni][r] = (acc2[mi][ni][r] - mu[ni])*rs[ni]*g4[r] + be4[r];
    }

    // ---- coalesced out writes via Yh overlay, two o-phases (mi-pairs) ----
    // packed row = wv*32 + (mi&1)*16 + (lane>>4)*4 + r; o_act = (row>>5)*64 + p*32 + (row&31)
    size_t outb = (size_t)b*CDIM*NSP + n0;
    #pragma unroll
    for (int p=0; p<2; ++p){
        __syncthreads();   // Bs/q~ dead (p0) / prev Yh reads done (p1)
        #pragma unroll
        for (int mi=2*p; mi<2*p+2; mi++)
            #pragma unroll
            for (int ni=0;ni<2;ni++){
                int row = wv*32 + (mi&1)*16 + (lane>>4)*4;
                int n = ni*16 + (lane&15);
                #pragma unroll
                for (int r=0;r<4;r++) sm.Yh[(row+r)*33 + n] = acc2[mi][ni][r];
            }
        __syncthreads();
        int n = t & 31, q = t >> 5;          // 8 groups x 16 rows
        #pragma unroll
        for (int i=0;i<16;i++){
            int row = q*16 + i;
            int o_act = (row>>5)*64 + p*32 + (row&31);
            out[outb + (size_t)o_act*NSP + n] = sm.Yh[row*33 + n];
        }
    }
}

extern "C" void kernel_launch(void* const* d_in, const int* in_sizes, int n_in,
                              void* d_out, int out_size, void* d_ws, size_t ws_size,
                              hipStream_t stream){
    const float* x     = (const float*)d_in[0];
    const float* w_qkv = (const float*)d_in[1];
    const float* w_out = (const float*)d_in[2];
    const float* b_out = (const float*)d_in[3];
    const float* gamma = (const float*)d_in[4];
    const float* beta  = (const float*)d_in[5];
    float* out = (float*)d_out;
    char* ws = (char*)d_ws;
    // ws layout (bytes):
    //   xT    bf16 [16][4096][256]     : 0          .. 33,554,432
    //   ctx_p f32  [128][32][1024]     : 67,108,864 .. 83,886,080
    //   W2    bf16 [16][256][256]      : 134,742,016 .. 136,839,168
    //   w2    bf16 [768][256]          : 136,839,168 .. 137,232,384
    //   (qT eliminated)
    bf16*  xT    = (bf16*) ws;
    float* ctx_p = (float*)(ws + 67108864ull);
    bf16*  W2    = (bf16*)(ws + 134742016ull);
    bf16*  w2    = (bf16*)(ws + 136839168ull);

    k_wcvt     <<<dim3(192),       256,  0, stream>>>(w_qkv, w2);
    k_transpose<<<dim3(64, 4, NB), 256,  0, stream>>>(x, xT);
    k_kvctx    <<<dim3(512),       1024, 0, stream>>>(w2, xT, ctx_p);
    k_merge    <<<dim3(128),       256,  0, stream>>>(w_out, ctx_p, W2);
    k_qout_ln  <<<dim3(2048),      256,  0, stream>>>(w2, xT, W2, b_out, gamma, beta, out);
}

// Round 11
// 234.357 us; speedup vs baseline: 1.2522x; 1.2522x over previous
//
#include <hip/hip_runtime.h>
#include <hip/hip_bf16.h>

#define NB 16
#define CDIM 256
#define NHEADS 8
#define DH 32
#define NSP 4096
#define O3 768

typedef __bf16 bf16;
typedef bf16 bf16x4 __attribute__((ext_vector_type(4)));
typedef bf16 bf16x8 __attribute__((ext_vector_type(8)));
typedef float f32x4 __attribute__((ext_vector_type(4)));
typedef float f32x16 __attribute__((ext_vector_type(16)));

static __device__ __forceinline__ float bf2f(bf16 x){ return (float)x; }
static __device__ __forceinline__ bf16 f2bf(float x){ return (bf16)x; }

// async global->LDS, 16B per lane; lds dst wave-uniform base + lane*16
static __device__ __forceinline__ void gld16(const bf16* g, bf16* l){
    __builtin_amdgcn_global_load_lds((const __attribute__((address_space(1))) void*)g,
                                     (__attribute__((address_space(3))) void*)l, 16, 0, 0);
}

// ---------------- K0: transpose+convert x[b][c][n] (fp32) -> xT[b][n][c] (bf16) ----------------
__global__ void k_transpose(const float* __restrict__ x, bf16* __restrict__ xT){
    __shared__ bf16 tile[64][72];
    int b = blockIdx.z;
    int c0 = blockIdx.y * 64;
    int n0 = blockIdx.x * 64;
    int t = threadIdx.x;
    const float* xb = x + (size_t)b * CDIM * NSP;
    #pragma unroll
    for (int i = 0; i < 4; ++i){
        int lin = i*256 + t;
        int c = lin >> 4;
        int n4 = (lin & 15) * 4;
        f32x4 f = *(const f32x4*)(xb + (size_t)(c0 + c)*NSP + n0 + n4);
        bf16x4 v4;
        #pragma unroll
        for (int j = 0; j < 4; ++j) v4[j] = f2bf(f[j]);
        *(bf16x4*)&tile[c][n4] = v4;
    }
    __syncthreads();
    bf16* xTb = xT + (size_t)b * NSP * CDIM;
    #pragma unroll
    for (int i = 0; i < 2; ++i){
        int lin = i*256 + t;
        int n = lin >> 3;
        int c8 = (lin & 7) * 8;
        bf16x8 v;
        #pragma unroll
        for (int j = 0; j < 8; ++j) v[j] = tile[c8+j][n];
        *(bf16x8*)(xTb + (size_t)(n0+n)*CDIM + c0 + c8) = v;
    }
}

// ---------------- K0b: convert w_qkv fp32 -> bf16 ----------------
__global__ void k_wcvt(const float* __restrict__ w, bf16* __restrict__ w2){
    int idx = (blockIdx.x*256 + threadIdx.x) * 4;
    f32x4 f = *(const f32x4*)(w + idx);
    bf16x4 v;
    #pragma unroll
    for (int j=0;j<4;j++) v[j] = f2bf(f[j]);
    *(bf16x4*)(w2 + idx) = v;
}

// ---------------- K2: fused k/v GEMM + k softmax + context partials, 128-n panels ----------------
// Block: one 128-n panel (64KB Bs) x all 512 k/v rows. 1024 thr = 16 waves;
// wave = 32 o x 128 n, acc[2][8], 128 MFMA. Waves 0-7: k (rows 256..511), 8-15: v (512..767).
// k softmax per 64-wide y-line (two lines per panel, R1 grp pattern).
// 2 phases x 4 heads: dump k_sm/v to cb[128][128] each (XOR-swz, 64KB), ctx via mfma 32x32x16
// (8 MFMA per head over n=128), write fp32 partials ctx_p[b][h][ntile][32][32]. kv never in HBM.
__global__ __launch_bounds__(1024,4) void k_kvctx(const bf16* __restrict__ w2,
                                                  const bf16* __restrict__ xT,
                                                  float* __restrict__ ctx_p){
    __shared__ union {
        bf16 Bs[32768];      // 128 rows * 32 slots * 8 el = 64 KB
        bf16 cb[32768];      // k_sm[128][128] @ el 0, v[128][128] @ el 16384
    } sm;
    int bid = blockIdx.x;
    int xcd = bid & 7, slot = bid >> 3;      // 64 slots per XCD
    int g = xcd*64 + slot;                   // 0..511
    int b = g >> 5;
    int ntile = g & 31;
    int n0 = ntile * 128;
    int t = threadIdx.x;
    int wv = t >> 6, lane = t & 63;

    // ---- stage panel [128 n][256 c]: per wave 4 gld16 (rows wv*8 .. wv*8+7) ----
    #pragma unroll
    for (int j=0;j<4;j++){
        int base_r = wv*8 + j*2;
        int r = base_r + (lane>>5);
        int c = (lane & 31) ^ (r & 7);
        gld16(xT + ((size_t)b*NSP + n0 + r)*CDIM + c*8, &sm.Bs[(size_t)base_r*256]);
    }
    __syncthreads();

    int brow[8], brx[8];
    #pragma unroll
    for (int ni=0;ni<8;ni++){
        int r = ni*16 + (lane&15);
        brow[ni] = r*32; brx[ni] = r & 7;
    }
    int arow = 256 + wv*32 + (lane&15);      // waves 0-7: k (256..511); 8-15: v (512..767)
    int acol = (lane>>4)*8;

    f32x4 acc[2][8];
    #pragma unroll
    for (int i=0;i<16;i++) ((f32x4*)acc)[i] = (f32x4){0.f,0.f,0.f,0.f};

    bf16x8 af0 = *(const bf16x8*)(w2 + (size_t)(arow     )*CDIM + acol);
    bf16x8 af1 = *(const bf16x8*)(w2 + (size_t)(arow + 16)*CDIM + acol);
    #pragma unroll
    for (int k0=0;k0<8;k0++){
        bf16x8 an0, an1;
        if (k0 < 7){
            an0 = *(const bf16x8*)(w2 + (size_t)(arow     )*CDIM + (k0+1)*32 + acol);
            an1 = *(const bf16x8*)(w2 + (size_t)(arow + 16)*CDIM + (k0+1)*32 + acol);
        }
        int cbase = (lane>>4) + k0*4;
        bf16x8 bfr[8];
        #pragma unroll
        for (int ni=0;ni<8;ni++)
            bfr[ni] = *(const bf16x8*)&sm.Bs[(size_t)(brow[ni] + (cbase ^ brx[ni]))*8];
        #pragma unroll
        for (int ni=0;ni<8;ni++)
            acc[0][ni] = __builtin_amdgcn_mfma_f32_16x16x32_bf16(af0, bfr[ni], acc[0][ni], 0, 0, 0);
        #pragma unroll
        for (int ni=0;ni<8;ni++)
            acc[1][ni] = __builtin_amdgcn_mfma_f32_16x16x32_bf16(af1, bfr[ni], acc[1][ni], 0, 0, 0);
        af0 = an0; af1 = an1;
    }

    // ---- k softmax over y-lines (waves 0-7): grp 0 = ni 0..3 (n 0..63), grp 1 = ni 4..7 ----
    if (wv < 8){
        #pragma unroll
        for (int mi=0;mi<2;mi++)
            #pragma unroll
            for (int r=0;r<4;r++)
                #pragma unroll
                for (int grp=0;grp<2;grp++){
                    float mx = -1e30f;
                    #pragma unroll
                    for (int q=0;q<4;q++) mx = fmaxf(mx, acc[mi][grp*4+q][r]);
                    #pragma unroll
                    for (int msk=1; msk<16; msk<<=1) mx = fmaxf(mx, __shfl_xor(mx, msk, 64));
                    float s = 0.f;
                    #pragma unroll
                    for (int q=0;q<4;q++){
                        float e = __expf(acc[mi][grp*4+q][r] - mx);
                        acc[mi][grp*4+q][r] = e; s += e;
                    }
                    #pragma unroll
                    for (int msk=1; msk<16; msk<<=1) s += __shfl_xor(s, msk, 64);
                    float inv = 1.f/s;
                    #pragma unroll
                    for (int q=0;q<4;q++) acc[mi][grp*4+q][r] *= inv;
                }
    }

    // ---- 2 phases x 4 heads: dump + ctx ----
    #pragma unroll
    for (int ph=0; ph<2; ++ph){
        __syncthreads();   // Bs dead (ph0) / prev-phase cb reads done (ph1)
        if (((wv>>2)&1) == ph){       // dumping waves this phase: k wv ph*4..+3, v wv 8+ph*4..+3
            int isv  = wv >> 3;
            int w03  = wv & 3;
            int base = isv * 16384;
            #pragma unroll
            for (int mi=0;mi<2;mi++)
                #pragma unroll
                for (int ni=0;ni<8;ni++)
                    #pragma unroll
                    for (int r=0;r<4;r++){
                        int row = w03*32 + mi*16 + (lane>>4)*4 + r;   // 0..127 in-phase
                        int n = ni*16 + (lane&15);
                        sm.cb[base + row*128 + (((n>>3) ^ (row&15))<<3) + (n&7)] = f2bf(acc[mi][ni][r]);
                    }
        }
        __syncthreads();
        if (wv < 4){
            // ctx for head h = ph*4 + wv: ctx[d][e] = sum_n k_sm[d][n] * v[e][n]
            f32x16 cacc;
            #pragma unroll
            for (int i=0;i<16;i++) cacc[i] = 0.f;
            int rr = wv*32 + (lane&31);
            #pragma unroll
            for (int s=0;s<8;s++){
                int nseg = s*2 + (lane>>5);
                int off = rr*128 + (((nseg ^ (rr&15))<<3));
                bf16x8 ka = *(const bf16x8*)&sm.cb[off];
                bf16x8 vb = *(const bf16x8*)&sm.cb[16384 + off];
                cacc = __builtin_amdgcn_mfma_f32_32x32x16_bf16(ka, vb, cacc, 0, 0, 0);
            }
            float* dst = ctx_p + ((size_t)(b*8 + ph*4 + wv)*32 + ntile)*1024;
            #pragma unroll
            for (int r=0;r<16;r++){
                int d = (r&3) + 8*(r>>2) + 4*(lane>>5);
                dst[d*32 + (lane&31)] = cacc[r];
            }
        }
    }
}

// ---------------- K5: reduce 32 partials + W2 = w_out x ctx (per b,h) ----------------
__global__ void k_merge(const float* __restrict__ w_out, const float* __restrict__ ctx_p,
                        bf16* __restrict__ W2){
    __shared__ float ctxs[32][32];
    int bh = blockIdx.x;
    int b = bh >> 3, h = bh & 7;
    int t = threadIdx.x;
    const float* base = ctx_p + (size_t)bh*32*1024;
    #pragma unroll
    for (int i=0;i<4;i++){
        int idx = i*256 + t;
        float s0 = 0.f, s1 = 0.f;
        #pragma unroll
        for (int p=0;p<16;p++){ s0 += base[(2*p)*1024 + idx]; s1 += base[(2*p+1)*1024 + idx]; }
        ((float*)ctxs)[idx] = s0 + s1;
    }
    __syncthreads();
    int o = t;
    const float* wrow = w_out + (size_t)o*CDIM + h*DH;
    float wv[32];
    #pragma unroll
    for (int d=0;d<32;d++) wv[d] = wrow[d];
    bf16* dst = W2 + ((size_t)b*CDIM + o)*CDIM + h*DH;
    #pragma unroll
    for (int g=0;g<4;g++){
        bf16x8 o8;
        #pragma unroll
        for (int jj=0;jj<8;jj++){
            int e = g*8 + jj;
            float s = 0.f;
            #pragma unroll
            for (int d=0;d<32;d++) s += wv[d]*ctxs[d][e];
            o8[jj] = f2bf(s);
        }
        *(bf16x8*)(dst + g*8) = o8;
    }
}

// ---------------- K6: fused q GEMM + q softmax + out GEMM + bias + register-LN ----------------
// Block: 32-n panel. Phase A: stage xT[n0..n0+32][0..256] (16KB); q-GEMM (acc[4][2]).
// q softmax per head (hp pattern). Phase B: dump q~ to swizzled slot format (16KB).
// Phase C: out-GEMM A=W2[b] global, B=q~ LDS, acc2[4][2].
// Phase D: LN stats in-register + normalize, coalesced writes via Yh[128][33] (two o-phases).
// launch_bounds(256,4): VGPR cap 128 — (256,8) in R9/R10 forced VGPR=32 and scratch-spilled
// (FETCH 25->90 MB, WRITE 65->196 MB). R8 measured 52 VGPR at (256,4): no spills.
__global__ __launch_bounds__(256,4) void k_qout_ln(const bf16* __restrict__ w2,
                                                   const bf16* __restrict__ xT,
                                                   const bf16* __restrict__ W2,
                                                   const float* __restrict__ bout,
                                                   const float* __restrict__ gamma,
                                                   const float* __restrict__ beta,
                                                   float* __restrict__ out){
    __shared__ union {
        bf16 Bs[8192];        // 32 rows * 32 slots * 8 el = 16 KB (xT panel, then q~)
        float Yh[128*33];     // 16.9 KB half-Y epilogue buffer
    } sm;
    __shared__ float red[2][4][2][16];
    __shared__ float mu_s[32], rstd_s[32];
    int bid = blockIdx.x;
    int xcd = bid & 7, slot = bid >> 3;      // 256 slots per XCD
    int b  = slot >> 4;
    int n0 = (xcd*16 + (slot & 15)) * 32;
    int t = threadIdx.x, wv = t>>6, lane = t&63;

    // ---- stage xT panel [n0..n0+32][0..256]: per wave 4 gld16 (rows wv*8..wv*8+7) ----
    const bf16* xTb = xT + (size_t)b * NSP * CDIM;
    #pragma unroll
    for (int j=0;j<4;j++){
        int base_r = wv*8 + j*2;
        int r = base_r + (lane>>5);
        int c = (lane & 31) ^ (r & 7);
        gld16(xTb + (size_t)(n0 + r)*CDIM + c*8, &sm.Bs[(size_t)base_r*256]);
    }
    __syncthreads();

    int brow[2], brx[2];
    #pragma unroll
    for (int ni=0;ni<2;ni++){
        int r = ni*16 + (lane&15);
        brow[ni] = r*32; brx[ni] = r & 7;
    }
    int arow = wv*64 + (lane&15);
    int acol = (lane>>4)*8;

    // ---- Phase A: q-GEMM, A = w2 q-rows (0..255) ----
    f32x4 acc[4][2];
    #pragma unroll
    for (int i=0;i<8;i++) ((f32x4*)acc)[i] = (f32x4){0.f,0.f,0.f,0.f};
    {
        bf16x8 af[4], an[4];
        #pragma unroll
        for (int mi=0;mi<4;mi++)
            af[mi] = *(const bf16x8*)(w2 + (size_t)(arow + mi*16)*CDIM + acol);
        #pragma unroll
        for (int k0=0;k0<8;k0++){
            if (k0 < 7){
                #pragma unroll
                for (int mi=0;mi<4;mi++)
                    an[mi] = *(const bf16x8*)(w2 + (size_t)(arow + mi*16)*CDIM + (k0+1)*32 + acol);
            }
            int cbase = (lane>>4) + k0*4;
            bf16x8 bfr[2];
            #pragma unroll
            for (int ni=0;ni<2;ni++)
                bfr[ni] = *(const bf16x8*)&sm.Bs[(size_t)(brow[ni] + (cbase ^ brx[ni]))*8];
            #pragma unroll
            for (int mi=0;mi<4;mi++)
                #pragma unroll
                for (int ni=0;ni<2;ni++)
                    acc[mi][ni] = __builtin_amdgcn_mfma_f32_16x16x32_bf16(af[mi], bfr[ni], acc[mi][ni], 0, 0, 0);
            #pragma unroll
            for (int mi=0;mi<4;mi++) af[mi] = an[mi];
        }
    }

    // ---- q softmax over d; wave's 64 o-rows = heads 2wv (mi 0,1), 2wv+1 (mi 2,3) ----
    #pragma unroll
    for (int ni=0;ni<2;ni++)
        #pragma unroll
        for (int hp=0;hp<2;hp++){
            float mx = -1e30f;
            #pragma unroll
            for (int mi=2*hp; mi<2*hp+2; mi++)
                #pragma unroll
                for (int r=0;r<4;r++) mx = fmaxf(mx, acc[mi][ni][r]);
            mx = fmaxf(mx, __shfl_xor(mx, 16, 64));
            mx = fmaxf(mx, __shfl_xor(mx, 32, 64));
            float s = 0.f;
            #pragma unroll
            for (int mi=2*hp; mi<2*hp+2; mi++)
                #pragma unroll
                for (int r=0;r<4;r++){
                    float e = __expf(acc[mi][ni][r] - mx);
                    acc[mi][ni][r] = e; s += e;
                }
            s += __shfl_xor(s, 16, 64);
            s += __shfl_xor(s, 32, 64);
            float inv = 1.f/s;
            #pragma unroll
            for (int mi=2*hp; mi<2*hp+2; mi++)
                #pragma unroll
                for (int r=0;r<4;r++) acc[mi][ni][r] *= inv;
        }

    // ---- Phase B: dump q~ into swizzled slot format: slot(n,cseg)=n*32+(cseg^(n&7)) ----
    __syncthreads();   // Bs (xT panel) dead
    #pragma unroll
    for (int mi=0;mi<4;mi++)
        #pragma unroll
        for (int ni=0;ni<2;ni++){
            int n_loc = ni*16 + (lane&15);
            int cseg  = wv*8 + mi*2 + (lane>>5);          // (o>>3), o = wv*64+mi*16+(lane>>4)*4
            bf16x4 v4;
            #pragma unroll
            for (int r=0;r<4;r++) v4[r] = f2bf(acc[mi][ni][r]);
            *(bf16x4*)&sm.Bs[(size_t)(n_loc*32 + (cseg ^ (n_loc&7)))*8 + ((lane>>4)&1)*4] = v4;
        }
    __syncthreads();

    // ---- Phase C: out-GEMM, A = W2[b] (global, L2-hot), B = q~ (LDS) ----
    const bf16* Ab = W2 + (size_t)b*CDIM*CDIM;
    f32x4 acc2[4][2];
    #pragma unroll
    for (int i=0;i<8;i++) ((f32x4*)acc2)[i] = (f32x4){0.f,0.f,0.f,0.f};
    {
        bf16x8 af[4], an[4];
        #pragma unroll
        for (int mi=0;mi<4;mi++)
            af[mi] = *(const bf16x8*)(Ab + (size_t)(arow + mi*16)*CDIM + acol);
        #pragma unroll
        for (int k0=0;k0<8;k0++){
            if (k0 < 7){
                #pragma unroll
                for (int mi=0;mi<4;mi++)
                    an[mi] = *(const bf16x8*)(Ab + (size_t)(arow + mi*16)*CDIM + (k0+1)*32 + acol);
            }
            int cbase = (lane>>4) + k0*4;
            bf16x8 bfr[2];
            #pragma unroll
            for (int ni=0;ni<2;ni++)
                bfr[ni] = *(const bf16x8*)&sm.Bs[(size_t)(brow[ni] + (cbase ^ brx[ni]))*8];
            #pragma unroll
            for (int mi=0;mi<4;mi++)
                #pragma unroll
                for (int ni=0;ni<2;ni++)
                    acc2[mi][ni] = __builtin_amdgcn_mfma_f32_16x16x32_bf16(af[mi], bfr[ni], acc2[mi][ni], 0, 0, 0);
            #pragma unroll
            for (int mi=0;mi<4;mi++) af[mi] = an[mi];
        }
    }

    // ---- Phase D: LN stats + normalize in-register ----
    // lane's o-rows: o = wv*64 + mi*16 + (lane>>4)*4 + r; n = ni*16 + (lane&15).
    float sA[2] = {0.f, 0.f}, sB[2] = {0.f, 0.f};
    #pragma unroll
    for (int mi=0;mi<4;mi++){
        f32x4 b4 = *(const f32x4*)&bout[wv*64 + mi*16 + (lane>>4)*4];
        #pragma unroll
        for (int ni=0;ni<2;ni++)
            #pragma unroll
            for (int r=0;r<4;r++){
                float y = acc2[mi][ni][r] + b4[r];
                acc2[mi][ni][r] = y;
                sA[ni] += y; sB[ni] += y*y;
            }
    }
    #pragma unroll
    for (int ni=0;ni<2;ni++){
        sA[ni] += __shfl_xor(sA[ni], 16, 64); sA[ni] += __shfl_xor(sA[ni], 32, 64);
        sB[ni] += __shfl_xor(sB[ni], 16, 64); sB[ni] += __shfl_xor(sB[ni], 32, 64);
    }
    if (lane < 16){
        #pragma unroll
        for (int ni=0;ni<2;ni++){
            red[0][wv][ni][lane] = sA[ni];
            red[1][wv][ni][lane] = sB[ni];
        }
    }
    __syncthreads();
    if (t < 32){
        float S = 0.f, S2 = 0.f;
        #pragma unroll
        for (int w=0;w<4;w++){ S += red[0][w][t>>4][t&15]; S2 += red[1][w][t>>4][t&15]; }
        float mu = S * (1.f/256.f);
        float var = S2*(1.f/256.f) - mu*mu;
        mu_s[t] = mu; rstd_s[t] = rsqrtf(var + 1e-5f);
    }
    __syncthreads();
    float mu[2], rs[2];
    #pragma unroll
    for (int ni=0;ni<2;ni++){
        mu[ni] = mu_s[ni*16 + (lane&15)];
        rs[ni] = rstd_s[ni*16 + (lane&15)];
    }
    #pragma unroll
    for (int mi=0;mi<4;mi++){
        int o0 = wv*64 + mi*16 + (lane>>4)*4;
        f32x4 g4  = *(const f32x4*)&gamma[o0];
        f32x4 be4 = *(const f32x4*)&beta[o0];
        #pragma unroll
        for (int ni=0;ni<2;ni++)
            #pragma unroll
            for (int r=0;r<4;r++)
                acc2[mi][ni][r] = (acc2[mi][ni][r] - mu[ni])*rs[ni]*g4[r] + be4[r];
    }

    // ---- coalesced out writes via Yh overlay, two o-phases (mi-pairs) ----
    // packed row = wv*32 + (mi&1)*16 + (lane>>4)*4 + r; o_act = (row>>5)*64 + p*32 + (row&31)
    size_t outb = (size_t)b*CDIM*NSP + n0;
    #pragma unroll
    for (int p=0; p<2; ++p){
        __syncthreads();   // Bs/q~ dead (p0) / prev Yh reads done (p1)
        #pragma unroll
        for (int mi=2*p; mi<2*p+2; mi++)
            #pragma unroll
            for (int ni=0;ni<2;ni++){
                int row = wv*32 + (mi&1)*16 + (lane>>4)*4;
                int n = ni*16 + (lane&15);
                #pragma unroll
                for (int r=0;r<4;r++) sm.Yh[(row+r)*33 + n] = acc2[mi][ni][r];
            }
        __syncthreads();
        int n = t & 31, q = t >> 5;          // 8 groups x 16 rows
        #pragma unroll
        for (int i=0;i<16;i++){
            int row = q*16 + i;
            int o_act = (row>>5)*64 + p*32 + (row&31);
            out[outb + (size_t)o_act*NSP + n] = sm.Yh[row*33 + n];
        }
    }
}

extern "C" void kernel_launch(void* const* d_in, const int* in_sizes, int n_in,
                              void* d_out, int out_size, void* d_ws, size_t ws_size,
                              hipStream_t stream){
    const float* x     = (const float*)d_in[0];
    const float* w_qkv = (const float*)d_in[1];
    const float* w_out = (const float*)d_in[2];
    const float* b_out = (const float*)d_in[3];
    const float* gamma = (const float*)d_in[4];
    const float* beta  = (const float*)d_in[5];
    float* out = (float*)d_out;
    char* ws = (char*)d_ws;
    // ws layout (bytes):
    //   xT    bf16 [16][4096][256]     : 0          .. 33,554,432
    //   ctx_p f32  [128][32][1024]     : 67,108,864 .. 83,886,080
    //   W2    bf16 [16][256][256]      : 134,742,016 .. 136,839,168
    //   w2    bf16 [768][256]          : 136,839,168 .. 137,232,384
    //   (qT eliminated)
    bf16*  xT    = (bf16*) ws;
    float* ctx_p = (float*)(ws + 67108864ull);
    bf16*  W2    = (bf16*)(ws + 134742016ull);
    bf16*  w2    = (bf16*)(ws + 136839168ull);

    k_wcvt     <<<dim3(192),       256,  0, stream>>>(w_qkv, w2);
    k_transpose<<<dim3(64, 4, NB), 256,  0, stream>>>(x, xT);
    k_kvctx    <<<dim3(512),       1024, 0, stream>>>(w2, xT, ctx_p);
    k_merge    <<<dim3(128),       256,  0, stream>>>(w_out, ctx_p, W2);
    k_qout_ln  <<<dim3(2048),      256,  0, stream>>>(w2, xT, W2, b_out, gamma, beta, out);
}

// Round 12
// 209.995 us; speedup vs baseline: 1.3975x; 1.1160x over previous
//
#include <hip/hip_runtime.h>
#include <hip/hip_bf16.h>

#define NB 16
#define CDIM 256
#define NHEADS 8
#define DH 32
#define NSP 4096
#define O3 768

typedef __bf16 bf16;
typedef bf16 bf16x4 __attribute__((ext_vector_type(4)));
typedef bf16 bf16x8 __attribute__((ext_vector_type(8)));
typedef float f32x4 __attribute__((ext_vector_type(4)));
typedef float f32x16 __attribute__((ext_vector_type(16)));

static __device__ __forceinline__ float bf2f(bf16 x){ return (float)x; }
static __device__ __forceinline__ bf16 f2bf(float x){ return (bf16)x; }

// async global->LDS, 16B per lane; lds dst wave-uniform base + lane*16
static __device__ __forceinline__ void gld16(const bf16* g, bf16* l){
    __builtin_amdgcn_global_load_lds((const __attribute__((address_space(1))) void*)g,
                                     (__attribute__((address_space(3))) void*)l, 16, 0, 0);
}

// ---------------- K0: transpose+convert x[b][c][n] (fp32) -> xT[b][n][c] (bf16) ----------------
__global__ void k_transpose(const float* __restrict__ x, bf16* __restrict__ xT){
    __shared__ bf16 tile[64][72];
    int b = blockIdx.z;
    int c0 = blockIdx.y * 64;
    int n0 = blockIdx.x * 64;
    int t = threadIdx.x;
    const float* xb = x + (size_t)b * CDIM * NSP;
    #pragma unroll
    for (int i = 0; i < 4; ++i){
        int lin = i*256 + t;
        int c = lin >> 4;
        int n4 = (lin & 15) * 4;
        f32x4 f = *(const f32x4*)(xb + (size_t)(c0 + c)*NSP + n0 + n4);
        bf16x4 v4;
        #pragma unroll
        for (int j = 0; j < 4; ++j) v4[j] = f2bf(f[j]);
        *(bf16x4*)&tile[c][n4] = v4;
    }
    __syncthreads();
    bf16* xTb = xT + (size_t)b * NSP * CDIM;
    #pragma unroll
    for (int i = 0; i < 2; ++i){
        int lin = i*256 + t;
        int n = lin >> 3;
        int c8 = (lin & 7) * 8;
        bf16x8 v;
        #pragma unroll
        for (int j = 0; j < 8; ++j) v[j] = tile[c8+j][n];
        *(bf16x8*)(xTb + (size_t)(n0+n)*CDIM + c0 + c8) = v;
    }
}

// ---------------- K0b: convert w_qkv fp32 -> bf16 ----------------
__global__ void k_wcvt(const float* __restrict__ w, bf16* __restrict__ w2){
    int idx = (blockIdx.x*256 + threadIdx.x) * 4;
    f32x4 f = *(const f32x4*)(w + idx);
    bf16x4 v;
    #pragma unroll
    for (int j=0;j<4;j++) v[j] = f2bf(f[j]);
    *(bf16x4*)(w2 + idx) = v;
}

// ---------------- K2: fused k/v GEMM + k softmax + context partials, 128-n panels ----------------
// Block: one 128-n panel (64KB Bs) x all 512 k/v rows. 1024 thr = 16 waves;
// wave = 32 o x 128 n, acc[2][8], 128 MFMA. Waves 0-7: k (rows 256..511), 8-15: v (512..767).
// k softmax per 64-wide y-line (two lines per panel, R1 grp pattern).
// 2 phases x 4 heads: dump k_sm/v to cb[128][128] each (XOR-swz, 64KB), ctx via mfma 32x32x16
// (8 MFMA per head over n=128), write fp32 partials ctx_p[b][h][ntile][32][32]. kv never in HBM.
__global__ __launch_bounds__(1024,4) void k_kvctx(const bf16* __restrict__ w2,
                                                  const bf16* __restrict__ xT,
                                                  float* __restrict__ ctx_p){
    __shared__ union {
        bf16 Bs[32768];      // 128 rows * 32 slots * 8 el = 64 KB
        bf16 cb[32768];      // k_sm[128][128] @ el 0, v[128][128] @ el 16384
    } sm;
    int bid = blockIdx.x;
    int xcd = bid & 7, slot = bid >> 3;      // 64 slots per XCD
    int g = xcd*64 + slot;                   // 0..511
    int b = g >> 5;
    int ntile = g & 31;
    int n0 = ntile * 128;
    int t = threadIdx.x;
    int wv = t >> 6, lane = t & 63;

    // ---- stage panel [128 n][256 c]: per wave 4 gld16 (rows wv*8 .. wv*8+7) ----
    #pragma unroll
    for (int j=0;j<4;j++){
        int base_r = wv*8 + j*2;
        int r = base_r + (lane>>5);
        int c = (lane & 31) ^ (r & 7);
        gld16(xT + ((size_t)b*NSP + n0 + r)*CDIM + c*8, &sm.Bs[(size_t)base_r*256]);
    }
    __syncthreads();

    int brow[8], brx[8];
    #pragma unroll
    for (int ni=0;ni<8;ni++){
        int r = ni*16 + (lane&15);
        brow[ni] = r*32; brx[ni] = r & 7;
    }
    int arow = 256 + wv*32 + (lane&15);      // waves 0-7: k (256..511); 8-15: v (512..767)
    int acol = (lane>>4)*8;

    f32x4 acc[2][8];
    #pragma unroll
    for (int i=0;i<16;i++) ((f32x4*)acc)[i] = (f32x4){0.f,0.f,0.f,0.f};

    bf16x8 af0 = *(const bf16x8*)(w2 + (size_t)(arow     )*CDIM + acol);
    bf16x8 af1 = *(const bf16x8*)(w2 + (size_t)(arow + 16)*CDIM + acol);
    #pragma unroll
    for (int k0=0;k0<8;k0++){
        bf16x8 an0, an1;
        if (k0 < 7){
            an0 = *(const bf16x8*)(w2 + (size_t)(arow     )*CDIM + (k0+1)*32 + acol);
            an1 = *(const bf16x8*)(w2 + (size_t)(arow + 16)*CDIM + (k0+1)*32 + acol);
        }
        int cbase = (lane>>4) + k0*4;
        bf16x8 bfr[8];
        #pragma unroll
        for (int ni=0;ni<8;ni++)
            bfr[ni] = *(const bf16x8*)&sm.Bs[(size_t)(brow[ni] + (cbase ^ brx[ni]))*8];
        #pragma unroll
        for (int ni=0;ni<8;ni++)
            acc[0][ni] = __builtin_amdgcn_mfma_f32_16x16x32_bf16(af0, bfr[ni], acc[0][ni], 0, 0, 0);
        #pragma unroll
        for (int ni=0;ni<8;ni++)
            acc[1][ni] = __builtin_amdgcn_mfma_f32_16x16x32_bf16(af1, bfr[ni], acc[1][ni], 0, 0, 0);
        af0 = an0; af1 = an1;
    }

    // ---- k softmax over y-lines (waves 0-7): grp 0 = ni 0..3 (n 0..63), grp 1 = ni 4..7 ----
    if (wv < 8){
        #pragma unroll
        for (int mi=0;mi<2;mi++)
            #pragma unroll
            for (int r=0;r<4;r++)
                #pragma unroll
                for (int grp=0;grp<2;grp++){
                    float mx = -1e30f;
                    #pragma unroll
                    for (int q=0;q<4;q++) mx = fmaxf(mx, acc[mi][grp*4+q][r]);
                    #pragma unroll
                    for (int msk=1; msk<16; msk<<=1) mx = fmaxf(mx, __shfl_xor(mx, msk, 64));
                    float s = 0.f;
                    #pragma unroll
                    for (int q=0;q<4;q++){
                        float e = __expf(acc[mi][grp*4+q][r] - mx);
                        acc[mi][grp*4+q][r] = e; s += e;
                    }
                    #pragma unroll
                    for (int msk=1; msk<16; msk<<=1) s += __shfl_xor(s, msk, 64);
                    float inv = 1.f/s;
                    #pragma unroll
                    for (int q=0;q<4;q++) acc[mi][grp*4+q][r] *= inv;
                }
    }

    // ---- 2 phases x 4 heads: dump + ctx ----
    #pragma unroll
    for (int ph=0; ph<2; ++ph){
        __syncthreads();   // Bs dead (ph0) / prev-phase cb reads done (ph1)
        if (((wv>>2)&1) == ph){       // dumping waves this phase: k wv ph*4..+3, v wv 8+ph*4..+3
            int isv  = wv >> 3;
            int w03  = wv & 3;
            int base = isv * 16384;
            #pragma unroll
            for (int mi=0;mi<2;mi++)
                #pragma unroll
                for (int ni=0;ni<8;ni++)
                    #pragma unroll
                    for (int r=0;r<4;r++){
                        int row = w03*32 + mi*16 + (lane>>4)*4 + r;   // 0..127 in-phase
                        int n = ni*16 + (lane&15);
                        sm.cb[base + row*128 + (((n>>3) ^ (row&15))<<3) + (n&7)] = f2bf(acc[mi][ni][r]);
                    }
        }
        __syncthreads();
        if (wv < 4){
            // ctx for head h = ph*4 + wv: ctx[d][e] = sum_n k_sm[d][n] * v[e][n]
            f32x16 cacc;
            #pragma unroll
            for (int i=0;i<16;i++) cacc[i] = 0.f;
            int rr = wv*32 + (lane&31);
            #pragma unroll
            for (int s=0;s<8;s++){
                int nseg = s*2 + (lane>>5);
                int off = rr*128 + (((nseg ^ (rr&15))<<3));
                bf16x8 ka = *(const bf16x8*)&sm.cb[off];
                bf16x8 vb = *(const bf16x8*)&sm.cb[16384 + off];
                cacc = __builtin_amdgcn_mfma_f32_32x32x16_bf16(ka, vb, cacc, 0, 0, 0);
            }
            float* dst = ctx_p + ((size_t)(b*8 + ph*4 + wv)*32 + ntile)*1024;
            #pragma unroll
            for (int r=0;r<16;r++){
                int d = (r&3) + 8*(r>>2) + 4*(lane>>5);
                dst[d*32 + (lane&31)] = cacc[r];
            }
        }
    }
}

// ---------------- K5: reduce 32 partials + W2 = w_out x ctx (per b,h); 512 thr ----------------
__global__ void k_merge(const float* __restrict__ w_out, const float* __restrict__ ctx_p,
                        bf16* __restrict__ W2){
    __shared__ float ctxs[32][32];
    int bh = blockIdx.x;
    int b = bh >> 3, h = bh & 7;
    int t = threadIdx.x;      // 512
    const float* base = ctx_p + (size_t)bh*32*1024;
    #pragma unroll
    for (int i=0;i<2;i++){
        int idx = i*512 + t;
        float s0 = 0.f, s1 = 0.f;
        #pragma unroll
        for (int p=0;p<16;p++){ s0 += base[(2*p)*1024 + idx]; s1 += base[(2*p+1)*1024 + idx]; }
        ((float*)ctxs)[idx] = s0 + s1;
    }
    __syncthreads();
    int o = t & 255, half = t >> 8;     // half: e 0..15 / 16..31
    const float* wrow = w_out + (size_t)o*CDIM + h*DH;
    float wv[32];
    #pragma unroll
    for (int d=0;d<32;d++) wv[d] = wrow[d];
    bf16* dst = W2 + ((size_t)b*CDIM + o)*CDIM + h*DH + half*16;
    #pragma unroll
    for (int g=0;g<2;g++){
        bf16x8 o8;
        #pragma unroll
        for (int jj=0;jj<8;jj++){
            int e = half*16 + g*8 + jj;
            float s = 0.f;
            #pragma unroll
            for (int d=0;d<32;d++) s += wv[d]*ctxs[d][e];
            o8[jj] = f2bf(s);
        }
        *(bf16x8*)(dst + g*8) = o8;
    }
}

// ---------------- K6: fused q GEMM + q softmax + out GEMM + bias + LN; 64-n panels ----------------
// 1024 blocks x 512 thr (8 waves). Block: xT[n0..n0+64][0..256] (32KB). Wave = 32 o x 64 n,
// acc[2][4]; head = wv for q softmax. Phase B: q~ -> swizzled slot format (32KB, union).
// Phase C: out-GEMM A=W2[b]. Phase D: reg-LN stats (shfl 16/32 + red) + normalize; coalesced
// writes via Yh[128][65] fp32 (33.3KB union) in two 128-row halves (waves 0-3 / 4-7).
// 2 blocks/CU resident of 4 assigned -> two generations (gen-2 staging overlaps gen-1 compute).
// A-operand L2 traffic halved vs 32-n tiles (1024 x 256KB).
__global__ __launch_bounds__(512,2) void k_qout_ln(const bf16* __restrict__ w2,
                                                   const bf16* __restrict__ xT,
                                                   const bf16* __restrict__ W2,
                                                   const float* __restrict__ bout,
                                                   const float* __restrict__ gamma,
                                                   const float* __restrict__ beta,
                                                   float* __restrict__ out){
    __shared__ union {
        bf16 Bs[16384];       // 64 rows * 32 slots * 8 el = 32 KB (xT panel, then q~)
        float Yh[128*65];     // 33.3 KB half epilogue buffer
    } sm;
    __shared__ float red[2][8][4][16];
    __shared__ float mu_s[64], rstd_s[64];
    int bid = blockIdx.x;
    int xcd = bid & 7, slot = bid >> 3;      // 128 slots per XCD
    int g = xcd*128 + slot;                  // 0..1023
    int b  = g >> 6;
    int n0 = (g & 63) * 64;
    int t = threadIdx.x, wv = t>>6, lane = t&63;

    // ---- stage xT panel [n0..n0+64][0..256]: per wave 4 gld16 (rows wv*8..wv*8+7) ----
    const bf16* xTb = xT + (size_t)b * NSP * CDIM;
    #pragma unroll
    for (int j=0;j<4;j++){
        int base_r = wv*8 + j*2;
        int r = base_r + (lane>>5);
        int c = (lane & 31) ^ (r & 7);
        gld16(xTb + (size_t)(n0 + r)*CDIM + c*8, &sm.Bs[(size_t)base_r*256]);
    }
    __syncthreads();

    int brow[4], brx[4];
    #pragma unroll
    for (int ni=0;ni<4;ni++){
        int r = ni*16 + (lane&15);
        brow[ni] = r*32; brx[ni] = r & 7;
    }
    int arow = wv*32 + (lane&15);            // + mi*16; 8 waves cover o 0..255
    int acol = (lane>>4)*8;

    // ---- Phase A: q-GEMM, A = w2 q-rows (0..255) ----
    f32x4 acc[2][4];
    #pragma unroll
    for (int i=0;i<8;i++) ((f32x4*)acc)[i] = (f32x4){0.f,0.f,0.f,0.f};
    {
        bf16x8 af[2], an[2];
        #pragma unroll
        for (int mi=0;mi<2;mi++)
            af[mi] = *(const bf16x8*)(w2 + (size_t)(arow + mi*16)*CDIM + acol);
        #pragma unroll
        for (int k0=0;k0<8;k0++){
            if (k0 < 7){
                #pragma unroll
                for (int mi=0;mi<2;mi++)
                    an[mi] = *(const bf16x8*)(w2 + (size_t)(arow + mi*16)*CDIM + (k0+1)*32 + acol);
            }
            int cbase = (lane>>4) + k0*4;
            bf16x8 bfr[4];
            #pragma unroll
            for (int ni=0;ni<4;ni++)
                bfr[ni] = *(const bf16x8*)&sm.Bs[(size_t)(brow[ni] + (cbase ^ brx[ni]))*8];
            #pragma unroll
            for (int mi=0;mi<2;mi++)
                #pragma unroll
                for (int ni=0;ni<4;ni++)
                    acc[mi][ni] = __builtin_amdgcn_mfma_f32_16x16x32_bf16(af[mi], bfr[ni], acc[mi][ni], 0, 0, 0);
            #pragma unroll
            for (int mi=0;mi<2;mi++) af[mi] = an[mi];
        }
    }

    // ---- q softmax over d (wave's 32 o-rows == head wv): in-lane mi,r + xor 16,32 ----
    #pragma unroll
    for (int ni=0;ni<4;ni++){
        float mx = -1e30f;
        #pragma unroll
        for (int mi=0;mi<2;mi++)
            #pragma unroll
            for (int r=0;r<4;r++) mx = fmaxf(mx, acc[mi][ni][r]);
        mx = fmaxf(mx, __shfl_xor(mx, 16, 64));
        mx = fmaxf(mx, __shfl_xor(mx, 32, 64));
        float s = 0.f;
        #pragma unroll
        for (int mi=0;mi<2;mi++)
            #pragma unroll
            for (int r=0;r<4;r++){
                float e = __expf(acc[mi][ni][r] - mx);
                acc[mi][ni][r] = e; s += e;
            }
        s += __shfl_xor(s, 16, 64);
        s += __shfl_xor(s, 32, 64);
        float inv = 1.f/s;
        #pragma unroll
        for (int mi=0;mi<2;mi++)
            #pragma unroll
            for (int r=0;r<4;r++) acc[mi][ni][r] *= inv;
    }

    // ---- Phase B: dump q~ into swizzled slot format: slot(n,cseg)=n*32+(cseg^(n&7)) ----
    __syncthreads();   // Bs (xT panel) dead
    #pragma unroll
    for (int mi=0;mi<2;mi++)
        #pragma unroll
        for (int ni=0;ni<4;ni++){
            int n_loc = ni*16 + (lane&15);
            int cseg  = wv*4 + mi*2 + ((lane>>4)>>1);     // (o>>3), o = wv*32+mi*16+(lane>>4)*4
            bf16x4 v4;
            #pragma unroll
            for (int r=0;r<4;r++) v4[r] = f2bf(acc[mi][ni][r]);
            *(bf16x4*)&sm.Bs[(size_t)(n_loc*32 + (cseg ^ (n_loc&7)))*8 + ((lane>>4)&1)*4] = v4;
        }
    __syncthreads();

    // ---- Phase C: out-GEMM, A = W2[b] (global, L2-hot), B = q~ (LDS) ----
    const bf16* Ab = W2 + (size_t)b*CDIM*CDIM;
    f32x4 acc2[2][4];
    #pragma unroll
    for (int i=0;i<8;i++) ((f32x4*)acc2)[i] = (f32x4){0.f,0.f,0.f,0.f};
    {
        bf16x8 af[2], an[2];
        #pragma unroll
        for (int mi=0;mi<2;mi++)
            af[mi] = *(const bf16x8*)(Ab + (size_t)(arow + mi*16)*CDIM + acol);
        #pragma unroll
        for (int k0=0;k0<8;k0++){
            if (k0 < 7){
                #pragma unroll
                for (int mi=0;mi<2;mi++)
                    an[mi] = *(const bf16x8*)(Ab + (size_t)(arow + mi*16)*CDIM + (k0+1)*32 + acol);
            }
            int cbase = (lane>>4) + k0*4;
            bf16x8 bfr[4];
            #pragma unroll
            for (int ni=0;ni<4;ni++)
                bfr[ni] = *(const bf16x8*)&sm.Bs[(size_t)(brow[ni] + (cbase ^ brx[ni]))*8];
            #pragma unroll
            for (int mi=0;mi<2;mi++)
                #pragma unroll
                for (int ni=0;ni<4;ni++)
                    acc2[mi][ni] = __builtin_amdgcn_mfma_f32_16x16x32_bf16(af[mi], bfr[ni], acc2[mi][ni], 0, 0, 0);
            #pragma unroll
            for (int mi=0;mi<2;mi++) af[mi] = an[mi];
        }
    }

    // ---- Phase D: LN stats + normalize in-register ----
    // lane's o-rows: o = wv*32 + mi*16 + (lane>>4)*4 + r; n = ni*16 + (lane&15).
    float sA[4] = {0.f,0.f,0.f,0.f}, sB[4] = {0.f,0.f,0.f,0.f};
    #pragma unroll
    for (int mi=0;mi<2;mi++){
        f32x4 b4 = *(const f32x4*)&bout[wv*32 + mi*16 + (lane>>4)*4];
        #pragma unroll
        for (int ni=0;ni<4;ni++)
            #pragma unroll
            for (int r=0;r<4;r++){
                float y = acc2[mi][ni][r] + b4[r];
                acc2[mi][ni][r] = y;
                sA[ni] += y; sB[ni] += y*y;
            }
    }
    #pragma unroll
    for (int ni=0;ni<4;ni++){
        sA[ni] += __shfl_xor(sA[ni], 16, 64); sA[ni] += __shfl_xor(sA[ni], 32, 64);
        sB[ni] += __shfl_xor(sB[ni], 16, 64); sB[ni] += __shfl_xor(sB[ni], 32, 64);
    }
    if (lane < 16){
        #pragma unroll
        for (int ni=0;ni<4;ni++){
            red[0][wv][ni][lane] = sA[ni];
            red[1][wv][ni][lane] = sB[ni];
        }
    }
    __syncthreads();
    if (t < 64){
        float S = 0.f, S2 = 0.f;
        #pragma unroll
        for (int w=0;w<8;w++){ S += red[0][w][t>>4][t&15]; S2 += red[1][w][t>>4][t&15]; }
        float mu = S * (1.f/256.f);
        float var = S2*(1.f/256.f) - mu*mu;
        mu_s[t] = mu; rstd_s[t] = rsqrtf(var + 1e-5f);
    }
    __syncthreads();
    float mu[4], rs[4];
    #pragma unroll
    for (int ni=0;ni<4;ni++){
        mu[ni] = mu_s[ni*16 + (lane&15)];
        rs[ni] = rstd_s[ni*16 + (lane&15)];
    }
    #pragma unroll
    for (int mi=0;mi<2;mi++){
        int o0 = wv*32 + mi*16 + (lane>>4)*4;
        f32x4 g4  = *(const f32x4*)&gamma[o0];
        f32x4 be4 = *(const f32x4*)&beta[o0];
        #pragma unroll
        for (int ni=0;ni<4;ni++)
            #pragma unroll
            for (int r=0;r<4;r++)
                acc2[mi][ni][r] = (acc2[mi][ni][r] - mu[ni])*rs[ni]*g4[r] + be4[r];
    }

    // ---- coalesced out writes via Yh overlay, two 128-row halves (waves 0-3 / 4-7) ----
    size_t outb = (size_t)b*CDIM*NSP + n0;
    #pragma unroll
    for (int p=0; p<2; ++p){
        __syncthreads();   // q~ dead (p0) / prev Yh reads done (p1)
        if ((wv>>2) == p){
            #pragma unroll
            for (int mi=0;mi<2;mi++)
                #pragma unroll
                for (int ni=0;ni<4;ni++){
                    int row = (wv&3)*32 + mi*16 + (lane>>4)*4;   // 0..127 in-half
                    int n = ni*16 + (lane&15);
                    #pragma unroll
                    for (int r=0;r<4;r++) sm.Yh[(row+r)*65 + n] = acc2[mi][ni][r];
                }
        }
        __syncthreads();
        int n = t & 63, q = t >> 6;          // 8 groups x 16 rows; 64 consecutive fp32 per row
        #pragma unroll
        for (int i=0;i<16;i++){
            int row = q*16 + i;
            out[outb + (size_t)(p*128 + row)*NSP + n] = sm.Yh[row*65 + n];
        }
    }
}

extern "C" void kernel_launch(void* const* d_in, const int* in_sizes, int n_in,
                              void* d_out, int out_size, void* d_ws, size_t ws_size,
                              hipStream_t stream){
    const float* x     = (const float*)d_in[0];
    const float* w_qkv = (const float*)d_in[1];
    const float* w_out = (const float*)d_in[2];
    const float* b_out = (const float*)d_in[3];
    const float* gamma = (const float*)d_in[4];
    const float* beta  = (const float*)d_in[5];
    float* out = (float*)d_out;
    char* ws = (char*)d_ws;
    // ws layout (bytes):
    //   xT    bf16 [16][4096][256]     : 0          .. 33,554,432
    //   ctx_p f32  [128][32][1024]     : 67,108,864 .. 83,886,080
    //   W2    bf16 [16][256][256]      : 134,742,016 .. 136,839,168
    //   w2    bf16 [768][256]          : 136,839,168 .. 137,232,384
    //   (qT eliminated)
    bf16*  xT    = (bf16*) ws;
    float* ctx_p = (float*)(ws + 67108864ull);
    bf16*  W2    = (bf16*)(ws + 134742016ull);
    bf16*  w2    = (bf16*)(ws + 136839168ull);

    k_wcvt     <<<dim3(192),       256,  0, stream>>>(w_qkv, w2);
    k_transpose<<<dim3(64, 4, NB), 256,  0, stream>>>(x, xT);
    k_kvctx    <<<dim3(512),       1024, 0, stream>>>(w2, xT, ctx_p);
    k_merge    <<<dim3(128),       512,  0, stream>>>(w_out, ctx_p, W2);
    k_qout_ln  <<<dim3(1024),      512,  0, stream>>>(w2, xT, W2, b_out, gamma, beta, out);
}